// Round 5
// baseline (8206.417 us; speedup 1.0000x reference)
//
#include <hip/hip_runtime.h>

#define NWG     256
#define TPB     512
#define NL0     128          // WGs [0,128) = layer0, [128,256) = layer1
#define T_STEPS 1024
#define HD      1024
#define DIN     256
#define K0      1280         // DIN + HD
#define K1      2048         // HD + HD
#define K0P     1288         // padded LDS row stride (shorts)
#define K1P     2056
#define RED_BYTES 8192                      // 4 hi-waves x 64 lanes x 8 f32
#define SMEM_BYTES (32*K1P*2 + RED_BYTES)   // 139,776 B

// workspace layout (bytes)
#define WS_FLAGS 0                       // 256 x 64B
#define WS_GEN   16384                   // 16 x 64B
#define WS_H0    32768                   // 2 x 131072
#define WS_H1    (32768 + 262144)
#define WS_ZERO  (32768 + 524288)        // memset [0, WS_ZERO)
#define WS_X8    1048576                 // 1024*32*64*8 bf16 = 33.5 MB
#define HBUF_US  65536                   // ushorts per h buffer
#define HBUF_U64 16384                   // u64 per h buffer
#define NGEN     16

typedef float  f32x4  __attribute__((ext_vector_type(4)));
typedef __bf16 bf16x8 __attribute__((ext_vector_type(8)));
typedef unsigned long long u64;

__device__ __forceinline__ unsigned short f2bf(float f){
  union { float f; unsigned u; } a; a.f = f;
  unsigned u = a.u;
  u += 0x7fffu + ((u >> 16) & 1u);   // RNE
  return (unsigned short)(u >> 16);
}
__device__ __forceinline__ float sigmf(float x){ return 1.0f/(1.0f + __expf(-x)); }
__device__ __forceinline__ float tanhf_fast(float x){ return 2.0f*sigmf(2.0f*x) - 1.0f; }

// coherent (IF-level, cross-XCD) accessors — per-access, no L2 invalidation
__device__ __forceinline__ u64 ld64c(const u64* p){
  return __hip_atomic_load(p, __ATOMIC_RELAXED, __HIP_MEMORY_SCOPE_AGENT);
}
__device__ __forceinline__ void st16c(unsigned short* p, unsigned short v){
  __hip_atomic_store(p, v, __ATOMIC_RELAXED, __HIP_MEMORY_SCOPE_AGENT);
}
__device__ __forceinline__ unsigned ldflag(const unsigned* p){
  return __hip_atomic_load(p, __ATOMIC_RELAXED, __HIP_MEMORY_SCOPE_AGENT);
}
__device__ __forceinline__ void stflag(unsigned* p, unsigned v){
  __hip_atomic_store(p, v, __ATOMIC_RELAXED, __HIP_MEMORY_SCOPE_AGENT);
}

// proven leader barrier: WG0 collects flags, fans out via NGEN gen lines.
__device__ __forceinline__ void gridbar(unsigned* flags, unsigned* gen,
                                        unsigned ep, int wg, int tid){
  asm volatile("s_waitcnt vmcnt(0)" ::: "memory");  // my h-stores are at IF
  __syncthreads();                                  // all waves of this WG drained
  if (wg == 0){
    if (tid > 0 && tid < NWG){
      while (ldflag(&flags[tid*16]) < ep) __builtin_amdgcn_s_sleep(4);
    }
    __syncthreads();
    if (tid < NGEN) stflag(&gen[tid*16], ep);
    __syncthreads();
  } else {
    if (tid == 0){
      stflag(&flags[wg*16], ep);
      while (ldflag(&gen[(wg & (NGEN-1))*16]) < ep) __builtin_amdgcn_s_sleep(4);
    }
    __syncthreads();
  }
}

// x [B,T,D] fp32 -> X8 bf16 in [T][D/8][B][8]
__global__ void xpose_kernel(const float* __restrict__ x, unsigned short* __restrict__ X8){
  int idx   = blockIdx.x*256 + threadIdx.x;
  int t     = idx >> 11;
  int rem   = idx & 2047;
  int plane = rem >> 6;
  int b     = rem & 63;
  const float* src = x + ((size_t)b << 18) + (t << 8) + (plane << 3);
  unsigned short tmp[8];
  #pragma unroll
  for (int j = 0; j < 8; ++j) tmp[j] = f2bf(src[j]);
  int4 v; __builtin_memcpy(&v, tmp, 16);
  ((int4*)X8)[idx] = v;
}

extern "C" __global__ void __launch_bounds__(TPB, 2)
lstm_mega(const float* __restrict__ Wih0, const float* __restrict__ Whh0,
          const float* __restrict__ bih0, const float* __restrict__ bhh0,
          const float* __restrict__ Wih1, const float* __restrict__ Whh1,
          const float* __restrict__ bih1, const float* __restrict__ bhh1,
          const unsigned short* __restrict__ X8, char* __restrict__ ws,
          float* __restrict__ out)
{
  extern __shared__ unsigned short Ws[];   // [32][KP] weights + reduce scratch
  const int tid   = threadIdx.x;
  const int wg    = blockIdx.x;
  const int layer = (wg >= NL0);
  const int wgl   = layer ? wg - NL0 : wg;
  const int KD    = layer ? K1  : K0;
  const int dlen  = layer ? HD  : DIN;
  const int KP    = layer ? K1P : K0P;
  float* Rs = (float*)&Ws[32*KP];          // [4][64][8] f32 reduce scratch

  unsigned* flags = (unsigned*)(ws + WS_FLAGS);
  unsigned* gen   = (unsigned*)(ws + WS_GEN);
  const u64* H0r  = (const u64*)(ws + WS_H0);
  const u64* H1r  = (const u64*)(ws + WS_H1);
  unsigned short* H0w = (unsigned short*)(ws + WS_H0);
  unsigned short* H1w = (unsigned short*)(ws + WS_H1);
  const int4* X4 = (const int4*)X8;

  // ---- stage this WG's 32 gate-rows (8 cols x 4 gates) into LDS (bf16) ----
  {
    const float* Wih = layer ? Wih1 : Wih0;
    const float* Whh = layer ? Whh1 : Whh0;
    for (int m = 0; m < 32; ++m){
      int gr = (m & 3)*HD + wgl*8 + (m >> 2);      // gate-major global row
      const float* ar = Wih + (size_t)gr*dlen;
      const float* br = Whh + (size_t)gr*HD;
      unsigned short* row = Ws + m*KP;
      for (int k = tid; k < KD; k += TPB)
        row[k] = f2bf(k < dlen ? ar[k] : br[k - dlen]);
    }
  }
  __syncthreads();

  const int lane  = tid & 63;
  const int wv    = tid >> 6;        // 0..7
  const int bwv   = wv & 3;          // batch-quad (waves w and w+4 share batches)
  const int khalf = wv >> 2;         // 0 = low K half, 1 = high K half
  const int q     = lane >> 4;       // k-quad (A/B frags); row-quad (C/D)
  const int nn    = lane & 15;       // A-row / B-batch / C-batch
  const int batch = bwv*16 + nn;

  float bias[2][4];
  {
    const float* bi = layer ? bih1 : bih0;
    const float* bh = layer ? bhh1 : bhh0;
    #pragma unroll
    for (int rt = 0; rt < 2; ++rt){
      int colr = wgl*8 + rt*4 + q;
      #pragma unroll
      for (int r = 0; r < 4; ++r)
        bias[rt][r] = bi[r*HD + colr] + bh[r*HD + colr];
    }
  }

  float cst[2] = {0.f, 0.f};
  float hv[2]  = {0.f, 0.f};

  auto do_step = [&](int t){
    f32x4 a00 = {0,0,0,0}, a01 = {0,0,0,0}, a10 = {0,0,0,0}, a11 = {0,0,0,0};

    auto MM = [&](int kb, bf16x8 b){
      bf16x8 a0, a1;
      __builtin_memcpy(&a0, &Ws[nn*KP + kb*32 + q*8], 16);
      __builtin_memcpy(&a1, &Ws[(16+nn)*KP + kb*32 + q*8], 16);
      if (kb & 1){ a01 = __builtin_amdgcn_mfma_f32_16x16x32_bf16(a0,b,a01,0,0,0);
                   a11 = __builtin_amdgcn_mfma_f32_16x16x32_bf16(a1,b,a11,0,0,0); }
      else       { a00 = __builtin_amdgcn_mfma_f32_16x16x32_bf16(a0,b,a00,0,0,0);
                   a10 = __builtin_amdgcn_mfma_f32_16x16x32_bf16(a1,b,a10,0,0,0); }
    };

    if (!layer){
      // ---- layer 0: gates = W0 @ [x_t ; h0(t-1)], K split 24/16 kb ----
      const u64* hb = H0r + ((t+1)&1)*HBUF_U64;
      u64 B[2][16];
      auto LD = [&](int c, int slot){            // h chunk c: planes c*8..c*8+7
        u64* d = B[slot];
        #pragma unroll
        for (int i = 0; i < 8; ++i){
          int e = (((c*8 + i)*4 + q)*64 + batch)*2;
          d[2*i]   = ld64c(hb + e);
          d[2*i+1] = ld64c(hb + e + 1);
        }
      };
      if (khalf == 0){
        const int4* xb = X4 + t*2048;
        int4 xr[8];
        #pragma unroll
        for (int kb = 0; kb < 8; ++kb)           // x part: L2-cached
          xr[kb] = xb[(kb*4 + q)*64 + batch];
        LD(0,0); LD(1,1);
        #pragma unroll
        for (int kb = 0; kb < 8; ++kb){
          bf16x8 b; __builtin_memcpy(&b, &xr[kb], 16);
          MM(kb, b);
        }
        #pragma unroll
        for (int c = 0; c < 2; ++c){
          u64* d = B[c];
          #pragma unroll
          for (int i = 0; i < 8; ++i){
            u64 pair[2] = {d[2*i], d[2*i+1]};
            bf16x8 b; __builtin_memcpy(&b, pair, 16);
            MM(8 + c*8 + i, b);
          }
        }
      } else {
        LD(2,0); LD(3,1);
        #pragma unroll
        for (int c = 0; c < 2; ++c){
          u64* d = B[c];
          #pragma unroll
          for (int i = 0; i < 8; ++i){
            u64 pair[2] = {d[2*i], d[2*i+1]};
            bf16x8 b; __builtin_memcpy(&b, pair, 16);
            MM(24 + c*8 + i, b);
          }
        }
      }
    } else {
      // ---- layer 1: K split — lo waves: y0(t) (kb 0-31); hi: h1(t-1) (kb 32-63)
      const u64* src = khalf ? (H1r + ((t+1)&1)*HBUF_U64)   // h1(t-1)
                             : (H0r + (t&1)*HBUF_U64);      // y0(t)
      const int kbb = khalf*32;
      u64 B[3][16];                              // 4 chunks of 8 kb, depth-3
      auto LD = [&](int c){
        u64* d = B[c % 3];
        #pragma unroll
        for (int i = 0; i < 8; ++i){
          int e = (((c*8 + i)*4 + q)*64 + batch)*2;
          d[2*i]   = ld64c(src + e);
          d[2*i+1] = ld64c(src + e + 1);
        }
      };
      LD(0); LD(1); LD(2);
      #pragma unroll
      for (int c = 0; c < 4; ++c){
        u64* d = B[c % 3];
        #pragma unroll
        for (int i = 0; i < 8; ++i){
          u64 pair[2] = {d[2*i], d[2*i+1]};
          bf16x8 b; __builtin_memcpy(&b, pair, 16);
          MM(kbb + c*8 + i, b);
        }
        if (c + 3 < 4) LD(c + 3);
      }
    }

    // ---- cross-wave split-K reduction via LDS ----
    f32x4 s0 = a00 + a01, s1 = a10 + a11;
    if (khalf == 1){
      float* dst = Rs + (bwv*64 + lane)*8;
      __builtin_memcpy(dst,     &s0, 16);
      __builtin_memcpy(dst + 4, &s1, 16);
    }
    __syncthreads();
    if (khalf == 0){
      const float* p = Rs + (bwv*64 + lane)*8;
      f32x4 r0, r1;
      __builtin_memcpy(&r0, p,     16);
      __builtin_memcpy(&r1, p + 4, 16);
      s0 += r0; s1 += r1;
      #pragma unroll
      for (int rt = 0; rt < 2; ++rt){
        f32x4 s = rt ? s1 : s0;
        float ii = sigmf(s[0] + bias[rt][0]);
        float ff = sigmf(s[1] + bias[rt][1]);
        float gg = tanhf_fast(s[2] + bias[rt][2]);
        float oo = sigmf(s[3] + bias[rt][3]);
        cst[rt] = ff*cst[rt] + ii*gg;
        hv[rt]  = oo*tanhf_fast(cst[rt]);
        unsigned short* dst = (layer ? H1w : H0w) + (t&1)*HBUF_US
                            + (wgl*64 + batch)*8 + (rt*4 + q);
        st16c(dst, f2bf(hv[rt]));
      }
    }
  };

  if (!layer){
    for (int s = 0; s < T_STEPS; ++s){
      do_step(s);
      gridbar(flags, gen, (unsigned)(s+1), wg, tid);
    }
  } else {
    for (int s = 0; s < T_STEPS; ++s){
      if (s > 0) do_step(s-1);
      gridbar(flags, gen, (unsigned)(s+1), wg, tid);
    }
    do_step(T_STEPS-1);
  }

  // out = [h0 | h1 | c0 | c1], each [B=64, H=1024] fp32 — lo waves only
  if (khalf == 0){
    int col0 = wgl*8 + q;
    int base = layer ? 65536 : 0;
    out[base          + batch*HD + col0    ] = hv[0];
    out[base          + batch*HD + col0 + 4] = hv[1];
    out[base + 131072 + batch*HD + col0    ] = cst[0];
    out[base + 131072 + batch*HD + col0 + 4] = cst[1];
  }
}

extern "C" void kernel_launch(void* const* d_in, const int* in_sizes, int n_in,
                              void* d_out, int out_size, void* d_ws, size_t ws_size,
                              hipStream_t stream)
{
  const float* x    = (const float*)d_in[0];
  const float* Wih0 = (const float*)d_in[1];
  const float* Whh0 = (const float*)d_in[2];
  const float* bih0 = (const float*)d_in[3];
  const float* bhh0 = (const float*)d_in[4];
  const float* Wih1 = (const float*)d_in[5];
  const float* Whh1 = (const float*)d_in[6];
  const float* bih1 = (const float*)d_in[7];
  const float* bhh1 = (const float*)d_in[8];
  float* out = (float*)d_out;

  char* ws = (char*)d_ws;
  unsigned short* X8 = (unsigned short*)(ws + WS_X8);

  // zero flags/gen + both h double-buffers (h(-1) = 0)
  hipMemsetAsync(d_ws, 0, WS_ZERO, stream);
  xpose_kernel<<<8192, 256, 0, stream>>>(x, X8);

  hipFuncSetAttribute((const void*)lstm_mega,
                      hipFuncAttributeMaxDynamicSharedMemorySize, SMEM_BYTES);

  const unsigned short* X8c = X8;
  void* args[] = {(void*)&Wih0,(void*)&Whh0,(void*)&bih0,(void*)&bhh0,
                  (void*)&Wih1,(void*)&Whh1,(void*)&bih1,(void*)&bhh1,
                  (void*)&X8c,(void*)&ws,(void*)&out};
  hipError_t err = hipLaunchCooperativeKernel((void*)lstm_mega, dim3(NWG), dim3(TPB),
                                              args, SMEM_BYTES, stream);
  if (err != hipSuccess){
    // Fallback: plain launch. 256 WGs x 139.8KB LDS => 1 WG/CU, grid == CU
    // count, all WGs co-resident by capacity.
    lstm_mega<<<dim3(NWG), dim3(TPB), SMEM_BYTES, stream>>>(
        Wih0, Whh0, bih0, bhh0, Wih1, Whh1, bih1, bhh1, X8c, ws, out);
  }
}

// Round 6
// 6613.190 us; speedup vs baseline: 1.2409x; 1.2409x over previous
//
#include <hip/hip_runtime.h>

#define NWG     256
#define TPB     256
#define NL0     128          // WGs [0,128) = layer0, [128,256) = layer1
#define T_STEPS 1024
#define HD      1024
#define DIN     256
#define K0      1280         // DIN + HD
#define K1      2048         // HD + HD
#define K0P     1288         // padded LDS row stride (shorts)
#define K1P     2056
#define SMEM_BYTES (32*K1P*2)   // 131,584 B (layer1 worst case)

#define HSLAB_BYTES 131072ull            // one h snapshot: 128 planes x 64 batch x 8 bf16
#define HSLAB_U64   16384
#define HIST_DEPTH  1025                 // slots 0..1024; slot(t)=(t+1)%1025 never wraps
#define HIST_BYTES  (HIST_DEPTH*HSLAB_BYTES)   // 134,348,800
#define X8_BYTES    33554432ull
#define FLAGS_BYTES 32768ull
#define NGEN        16

typedef float  f32x4  __attribute__((ext_vector_type(4)));
typedef __bf16 bf16x8 __attribute__((ext_vector_type(8)));
typedef unsigned long long u64;

__device__ __forceinline__ unsigned short f2bf(float f){
  union { float f; unsigned u; } a; a.f = f;
  unsigned u = a.u;
  u += 0x7fffu + ((u >> 16) & 1u);   // RNE
  return (unsigned short)(u >> 16);
}
__device__ __forceinline__ float sigmf(float x){ return 1.0f/(1.0f + __expf(-x)); }
__device__ __forceinline__ float tanhf_fast(float x){ return 2.0f*sigmf(2.0f*x) - 1.0f; }

// coherent (MALL-level, cross-XCD) accessors — per-access, no L2 invalidation
__device__ __forceinline__ u64 ld64c(const u64* p){
  return __hip_atomic_load(p, __ATOMIC_RELAXED, __HIP_MEMORY_SCOPE_AGENT);
}
__device__ __forceinline__ void st16c(unsigned short* p, unsigned short v){
  __hip_atomic_store(p, v, __ATOMIC_RELAXED, __HIP_MEMORY_SCOPE_AGENT);
}
__device__ __forceinline__ unsigned ldflag(const unsigned* p){
  return __hip_atomic_load(p, __ATOMIC_RELAXED, __HIP_MEMORY_SCOPE_AGENT);
}
__device__ __forceinline__ void stflag(unsigned* p, unsigned v){
  __hip_atomic_store(p, v, __ATOMIC_RELAXED, __HIP_MEMORY_SCOPE_AGENT);
}

// proven leader barrier: WG0 collects flags, fans out via NGEN gen lines.
__device__ __forceinline__ void gridbar(unsigned* flags, unsigned* gen,
                                        unsigned ep, int wg, int tid){
  asm volatile("s_waitcnt vmcnt(0)" ::: "memory");  // my sc1 h-stores are at MALL
  __syncthreads();
  if (wg == 0){
    if (tid > 0){
      while (ldflag(&flags[tid*16]) < ep) __builtin_amdgcn_s_sleep(4);
    }
    __syncthreads();
    if (tid < NGEN) stflag(&gen[tid*16], ep);
    __syncthreads();
  } else {
    if (tid == 0){
      stflag(&flags[wg*16], ep);
      while (ldflag(&gen[(wg & (NGEN-1))*16]) < ep) __builtin_amdgcn_s_sleep(4);
    }
    __syncthreads();
  }
}

// x [B,T,D] fp32 -> X8 bf16 in [T][D/8][B][8]
__global__ void xpose_kernel(const float* __restrict__ x, unsigned short* __restrict__ X8){
  int idx   = blockIdx.x*256 + threadIdx.x;
  int t     = idx >> 11;
  int rem   = idx & 2047;
  int plane = rem >> 6;
  int b     = rem & 63;
  const float* src = x + ((size_t)b << 18) + (t << 8) + (plane << 3);
  unsigned short tmp[8];
  #pragma unroll
  for (int j = 0; j < 8; ++j) tmp[j] = f2bf(src[j]);
  int4 v; __builtin_memcpy(&v, tmp, 16);
  ((int4*)X8)[idx] = v;
}

// H0C/H1C: true = coherent sc0 loads (double-buffer tier), false = plain loads
// (history tier: fresh address per step -> XCD-local L2 sharing is safe).
template<bool H0C, bool H1C>
__global__ void __launch_bounds__(TPB, 1)
lstm_mega(const float* __restrict__ Wih0, const float* __restrict__ Whh0,
          const float* __restrict__ bih0, const float* __restrict__ bhh0,
          const float* __restrict__ Wih1, const float* __restrict__ Whh1,
          const float* __restrict__ bih1, const float* __restrict__ bhh1,
          const unsigned short* __restrict__ X8,
          unsigned* flags, unsigned* gen,
          u64* H0, u64* H1, int d0, int d1,
          float* __restrict__ out)
{
  extern __shared__ unsigned short Ws[];   // [32][KP]
  const int tid   = threadIdx.x;
  const int wg    = blockIdx.x;
  const int layer = (wg >= NL0);
  const int wgl   = layer ? wg - NL0 : wg;
  const int KD    = layer ? K1  : K0;
  const int dlen  = layer ? HD  : DIN;
  const int KP    = layer ? K1P : K0P;
  const int4* X4  = (const int4*)X8;

  // ---- stage this WG's 32 gate-rows (8 cols x 4 gates) into LDS (bf16) ----
  {
    const float* Wih = layer ? Wih1 : Wih0;
    const float* Whh = layer ? Whh1 : Whh0;
    for (int m = 0; m < 32; ++m){
      int gr = (m & 3)*HD + wgl*8 + (m >> 2);      // gate-major global row
      const float* ar = Wih + (size_t)gr*dlen;
      const float* br = Whh + (size_t)gr*HD;
      unsigned short* row = Ws + m*KP;
      for (int k = tid; k < KD; k += TPB)
        row[k] = f2bf(k < dlen ? ar[k] : br[k - dlen]);
    }
  }
  __syncthreads();

  const int lane  = tid & 63;
  const int wv    = tid >> 6;
  const int q     = lane >> 4;       // k-quad (A/B frags); row-quad (C/D)
  const int nn    = lane & 15;       // A-row / B-batch / C-batch
  const int batch = wv*16 + nn;

  float bias[2][4];
  {
    const float* bi = layer ? bih1 : bih0;
    const float* bh = layer ? bhh1 : bhh0;
    #pragma unroll
    for (int rt = 0; rt < 2; ++rt){
      int colr = wgl*8 + rt*4 + q;
      #pragma unroll
      for (int r = 0; r < 4; ++r)
        bias[rt][r] = bi[r*HD + colr] + bh[r*HD + colr];
    }
  }

  float cst[2] = {0.f, 0.f};
  float hv[2]  = {0.f, 0.f};

  auto do_step = [&](int t){
    f32x4 a00 = {0,0,0,0}, a01 = {0,0,0,0}, a10 = {0,0,0,0}, a11 = {0,0,0,0};

    auto MM = [&](int kb, bf16x8 b){
      bf16x8 a0, a1;
      __builtin_memcpy(&a0, &Ws[nn*KP + kb*32 + q*8], 16);
      __builtin_memcpy(&a1, &Ws[(16+nn)*KP + kb*32 + q*8], 16);
      if (kb & 1){ a01 = __builtin_amdgcn_mfma_f32_16x16x32_bf16(a0,b,a01,0,0,0);
                   a11 = __builtin_amdgcn_mfma_f32_16x16x32_bf16(a1,b,a11,0,0,0); }
      else       { a00 = __builtin_amdgcn_mfma_f32_16x16x32_bf16(a0,b,a00,0,0,0);
                   a10 = __builtin_amdgcn_mfma_f32_16x16x32_bf16(a1,b,a10,0,0,0); }
    };

    if (!layer){
      // ---- layer 0: gates = W0 @ [x_t ; h0(t-1)] ----
      const int4* xb = X4 + (size_t)t*2048;
      const u64* hb  = H0 + (size_t)(t % d0)*HSLAB_U64;     // h0(t-1) slot

      int4 xr[8];
      #pragma unroll
      for (int kb = 0; kb < 8; ++kb)            // x part: L2-cached
        xr[kb] = xb[(kb*4 + q)*64 + batch];

      u64 B[3][16];                             // 8 kb-planes per chunk, depth-3
      auto LD = [&](int c){                     // chunk c: h-planes c*8 .. c*8+7
        u64* d = B[c % 3];
        #pragma unroll
        for (int i = 0; i < 8; ++i){
          const u64* p = hb + (((c*8 + i)*4 + q)*64 + batch)*2;
          d[2*i]   = H0C ? ld64c(p)     : p[0];
          d[2*i+1] = H0C ? ld64c(p + 1) : p[1];
        }
      };
      LD(0); LD(1);
      #pragma unroll
      for (int kb = 0; kb < 8; ++kb){
        bf16x8 b; __builtin_memcpy(&b, &xr[kb], 16);
        MM(kb, b);
      }
      LD(2);
      #pragma unroll
      for (int c = 0; c < 4; ++c){
        u64* d = B[c % 3];
        #pragma unroll
        for (int i = 0; i < 8; ++i){
          u64 pair[2] = {d[2*i], d[2*i+1]};
          bf16x8 b; __builtin_memcpy(&b, pair, 16);
          MM(8 + c*8 + i, b);
        }
        if (c + 3 < 4) LD(c + 3);
      }
    } else {
      // ---- layer 1: gates = W1 @ [y0(t) ; h1(t-1)] ----
      const u64* yb = H0 + (size_t)((t+1) % d0)*HSLAB_U64;  // y0(t) slot
      const u64* hb = H1 + (size_t)(t % d1)*HSLAB_U64;      // h1(t-1) slot

      u64 B[3][16];                              // 8 chunks of 8 kb, depth-3
      auto LD = [&](int c){                      // c<4 from yb, else from hb
        const u64* src = (c < 4) ? yb : hb;
        int p0 = (c & 3)*8;
        u64* d = B[c % 3];
        #pragma unroll
        for (int i = 0; i < 8; ++i){
          const u64* p = src + (((p0 + i)*4 + q)*64 + batch)*2;
          if (c < 4){ d[2*i] = H0C ? ld64c(p) : p[0];
                      d[2*i+1] = H0C ? ld64c(p + 1) : p[1]; }
          else      { d[2*i] = H1C ? ld64c(p) : p[0];
                      d[2*i+1] = H1C ? ld64c(p + 1) : p[1]; }
        }
      };
      LD(0); LD(1); LD(2);
      #pragma unroll
      for (int c = 0; c < 8; ++c){
        u64* d = B[c % 3];
        #pragma unroll
        for (int i = 0; i < 8; ++i){
          u64 pair[2] = {d[2*i], d[2*i+1]};
          bf16x8 b; __builtin_memcpy(&b, pair, 16);
          MM(c*8 + i, b);
        }
        if (c + 3 < 8) LD(c + 3);
      }
    }

    f32x4 s0 = a00 + a01, s1 = a10 + a11;
    u64* Hw = layer ? H1 : H0;
    int  wd = layer ? d1 : d0;
    unsigned short* wbase = (unsigned short*)(Hw + (size_t)((t+1) % wd)*HSLAB_U64);
    #pragma unroll
    for (int rt = 0; rt < 2; ++rt){
      f32x4 s = rt ? s1 : s0;
      float ii = sigmf(s[0] + bias[rt][0]);
      float ff = sigmf(s[1] + bias[rt][1]);
      float gg = tanhf_fast(s[2] + bias[rt][2]);
      float oo = sigmf(s[3] + bias[rt][3]);
      cst[rt] = ff*cst[rt] + ii*gg;
      hv[rt]  = oo*tanhf_fast(cst[rt]);
      st16c(wbase + (wgl*64 + batch)*8 + (rt*4 + q), f2bf(hv[rt]));
    }
  };

  if (!layer){
    for (int s = 0; s < T_STEPS; ++s){
      do_step(s);
      gridbar(flags, gen, (unsigned)(s+1), wg, tid);
    }
  } else {
    for (int s = 0; s < T_STEPS; ++s){
      if (s > 0) do_step(s-1);
      gridbar(flags, gen, (unsigned)(s+1), wg, tid);
    }
    do_step(T_STEPS-1);
  }

  // out = [h0 | h1 | c0 | c1], each [B=64, H=1024] fp32
  {
    int col0 = wgl*8 + q;
    int base = layer ? 65536 : 0;
    out[base          + batch*HD + col0    ] = hv[0];
    out[base          + batch*HD + col0 + 4] = hv[1];
    out[base + 131072 + batch*HD + col0    ] = cst[0];
    out[base + 131072 + batch*HD + col0 + 4] = cst[1];
  }
}

extern "C" void kernel_launch(void* const* d_in, const int* in_sizes, int n_in,
                              void* d_out, int out_size, void* d_ws, size_t ws_size,
                              hipStream_t stream)
{
  const float* x    = (const float*)d_in[0];
  const float* Wih0 = (const float*)d_in[1];
  const float* Whh0 = (const float*)d_in[2];
  const float* bih0 = (const float*)d_in[3];
  const float* bhh0 = (const float*)d_in[4];
  const float* Wih1 = (const float*)d_in[5];
  const float* Whh1 = (const float*)d_in[6];
  const float* bih1 = (const float*)d_in[7];
  const float* bhh1 = (const float*)d_in[8];
  float* out = (float*)d_out;

  char* ws = (char*)d_ws;
  unsigned* flags = (unsigned*)ws;
  unsigned* gen   = (unsigned*)(ws + 16384);

  const size_t need2 = FLAGS_BYTES + 2*HIST_BYTES + X8_BYTES;             // ~302 MB
  const size_t need1 = FLAGS_BYTES + HIST_BYTES + 2*HSLAB_BYTES + X8_BYTES; // ~168 MB

  u64 *H0p, *H1p; unsigned short* X8p; int d0, d1, tier;
  if (ws_size >= need2){
    tier = 2; d0 = HIST_DEPTH; d1 = HIST_DEPTH;
    H0p = (u64*)(ws + FLAGS_BYTES);
    H1p = (u64*)(ws + FLAGS_BYTES + HIST_BYTES);
    X8p = (unsigned short*)(ws + FLAGS_BYTES + 2*HIST_BYTES);
  } else if (ws_size >= need1){
    tier = 1; d0 = HIST_DEPTH; d1 = 2;
    H0p = (u64*)(ws + FLAGS_BYTES);
    H1p = (u64*)(ws + FLAGS_BYTES + HIST_BYTES);
    X8p = (unsigned short*)(ws + FLAGS_BYTES + HIST_BYTES + 2*HSLAB_BYTES);
  } else {
    tier = 0; d0 = 2; d1 = 2;
    H0p = (u64*)(ws + FLAGS_BYTES);
    H1p = (u64*)(ws + FLAGS_BYTES + 2*HSLAB_BYTES);
    X8p = (unsigned short*)(ws + FLAGS_BYTES + 4*HSLAB_BYTES);
  }

  // zero flags/gen + slot 0 of each h buffer (initial state h(-1)=0)
  hipMemsetAsync(flags, 0, FLAGS_BYTES, stream);
  hipMemsetAsync(H0p, 0, HSLAB_BYTES, stream);
  hipMemsetAsync(H1p, 0, HSLAB_BYTES, stream);
  xpose_kernel<<<8192, 256, 0, stream>>>(x, X8p);

  void* fn = (tier == 2) ? (void*)&lstm_mega<false,false>
           : (tier == 1) ? (void*)&lstm_mega<false,true>
                         : (void*)&lstm_mega<true,true>;
  hipFuncSetAttribute(fn, hipFuncAttributeMaxDynamicSharedMemorySize, SMEM_BYTES);

  const unsigned short* X8c = X8p;
  void* args[] = {(void*)&Wih0,(void*)&Whh0,(void*)&bih0,(void*)&bhh0,
                  (void*)&Wih1,(void*)&Whh1,(void*)&bih1,(void*)&bhh1,
                  (void*)&X8c,(void*)&flags,(void*)&gen,
                  (void*)&H0p,(void*)&H1p,(void*)&d0,(void*)&d1,(void*)&out};
  hipError_t err = hipLaunchCooperativeKernel(fn, dim3(NWG), dim3(TPB),
                                              args, SMEM_BYTES, stream);
  if (err != hipSuccess){
    // Fallback: plain launch. 256 WGs x 131.6KB LDS => 1 WG/CU, grid == CU
    // count, all WGs co-resident by capacity.
    if (tier == 2)
      lstm_mega<false,false><<<dim3(NWG), dim3(TPB), SMEM_BYTES, stream>>>(
        Wih0,Whh0,bih0,bhh0,Wih1,Whh1,bih1,bhh1,X8c,flags,gen,H0p,H1p,d0,d1,out);
    else if (tier == 1)
      lstm_mega<false,true><<<dim3(NWG), dim3(TPB), SMEM_BYTES, stream>>>(
        Wih0,Whh0,bih0,bhh0,Wih1,Whh1,bih1,bhh1,X8c,flags,gen,H0p,H1p,d0,d1,out);
    else
      lstm_mega<true,true><<<dim3(NWG), dim3(TPB), SMEM_BYTES, stream>>>(
        Wih0,Whh0,bih0,bhh0,Wih1,Whh1,bih1,bhh1,X8c,flags,gen,H0p,H1p,d0,d1,out);
  }
}